// Round 3
// baseline (97.529 us; speedup 1.0000x reference)
//
#include <hip/hip_runtime.h>

#define N_ATOMS 10000
#define N_EDGES 200000
#define EB 64          // edges staged per batch (per wave)
#define FP 52          // padded LDS row stride in dwords (44 data + pad; 52%32=20 -> conflict-free b128)
#define W_F 0.6283185307179586f   // pi/5 in f32

// ---- kernel A: starts[a] = lower_bound(seg_i, a) ----
__global__ __launch_bounds__(256) void seg_starts_kernel(
    const int* __restrict__ seg_i, int* __restrict__ starts)
{
    const int a = blockIdx.x * blockDim.x + threadIdx.x;
    if (a > N_ATOMS) return;
    int lo = 0, hi = N_EDGES;
    while (lo < hi) {
        int mid = (lo + hi) >> 1;
        if (seg_i[mid] < a) lo = mid + 1; else hi = mid;
    }
    starts[a] = lo;
}

// ---- kernel B: one WAVE per atom, 4 atoms per block, no inter-wave sync ----
// LDS row layout (per edge): dw 0-19 rad, dw 20-39 angular pairs (10 float2),
// dw 40-43 sp, dw 44-51 pad.
__global__ __launch_bounds__(256) void sph_expand_kernel(
    const float* __restrict__ R,
    const int*   __restrict__ starts,
    const int*   __restrict__ idx_j,
    const int*   __restrict__ species,
    const float* __restrict__ emb,
    float*       __restrict__ out)
{
    __shared__ float feat[4][EB][FP];   // 4*64*52*4 = 53248 B
    const int wave = threadIdx.x >> 6;
    const int lane = threadIdx.x & 63;
    const int atom = blockIdx.x * 4 + wave;
    float (*F)[FP] = feat[wave];

    // ---- tile decode: 43 active lanes, each owns 2m x 4n x 4c = 32 outputs ----
    // pair index table built in Phase A: pairs of angular values per (l, m-pair)
    int n0 = 0, m0 = 0, m1 = 0, nl = 0, pidx = 0, stride = 0; long base = 0;
    const bool active = (lane < 43);
    if (lane < 5)        { n0 = 4*lane;                                   m0 = 0; m1 = 0;                     nl = 20; pidx = 0;          base = 0;       stride = 80;  }
    else if (lane < 15)  { int q = lane-5;  int pr = q/5;  n0 = 4*(q%5);  m0 = 2*pr; m1 = (m0+1 < 3) ? m0+1 : 2; nl = 18; pidx = 1 + pr;  base = 800000;  stride = 216; }
    else if (lane < 27)  { int q = lane-15; int pr = q/4;  n0 = 4*(q%4);  m0 = 2*pr; m1 = (m0+1 < 5) ? m0+1 : 4; nl = 16; pidx = 3 + pr;  base = 2960000; stride = 320; }
    else if (lane < 43)  { int q = lane-27; int pr = q/4;  n0 = 4*(q%4);  m0 = 2*pr; m1 = (m0+1 < 7) ? m0+1 : 6; nl = 14; pidx = 6 + pr;  base = 6160000; stride = 392; }

    float4 acc[8];
    #pragma unroll
    for (int k = 0; k < 8; ++k) acc[k] = float4{0.f, 0.f, 0.f, 0.f};

    const int start = starts[atom];
    const int end   = starts[atom + 1];

    for (int e0 = start; e0 < end; e0 += EB) {
        const int cnt = min(EB, end - e0);

        // ---- Phase A: lane stages edge e0+lane ----
        if (lane < cnt) {
            const int g = e0 + lane;
            const int jj = idx_j[g];
            const float x = R[3*g + 0];
            const float y = R[3*g + 1];
            const float z = R[3*g + 2];
            const int sidx = species[jj];
            const float r   = sqrtf(x*x + y*y + z*z);
            const float inv = 1.0f / (r + 1e-12f);
            const float ux = x*inv, uy = y*inv, uz = z*inv;
            const float4 spv = *(const float4*)&emb[4 * sidx];

            // one sin + one cos; harmonics via Chebyshev recurrence
            const float t1 = W_F * r;
            const float s1 = sinf(t1);
            const float c1 = cosf(t1);
            const float fc = (r < 5.0f) ? (0.5f * (c1 + 1.0f)) : 0.0f;
            const float c2x = 2.0f * c1;

            float rb[20];
            {
                float sk_2 = 0.0f, sk_1 = s1;
                rb[0] = s1 * fc;
                #pragma unroll
                for (int k = 1; k < 20; ++k) {
                    const float sk = c2x * sk_1 - sk_2;
                    rb[k] = sk * fc;
                    sk_2 = sk_1; sk_1 = sk;
                }
            }

            const float x2 = ux*ux, y2 = uy*uy, z2 = uz*uz;
            const float c1a = 0.4886025119029199f;
            const float c2a = 1.0925484305920792f;
            float an[16];
            an[0]  = 0.28209479177387814f;
            an[1]  = c1a * uy;
            an[2]  = c1a * uz;
            an[3]  = c1a * ux;
            an[4]  = c2a * ux * uy;
            an[5]  = c2a * uy * uz;
            an[6]  = 0.31539156525252005f * (3.0f*z2 - 1.0f);
            an[7]  = c2a * ux * uz;
            an[8]  = 0.5462742152960396f * (x2 - y2);
            an[9]  = 0.5900435899266435f * uy * (3.0f*x2 - y2);
            an[10] = 2.890611442640554f  * ux * uy * uz;
            an[11] = 0.4570457994644658f * uy * (5.0f*z2 - 1.0f);
            an[12] = 0.3731763325901154f * uz * (5.0f*z2 - 3.0f);
            an[13] = 0.4570457994644658f * ux * (5.0f*z2 - 1.0f);
            an[14] = 1.445305721320277f  * uz * (x2 - y2);
            an[15] = 0.5900435899266435f * ux * (x2 - 3.0f*y2);

            float4* row = (float4*)&F[lane][0];
            row[0] = float4{rb[0],  rb[1],  rb[2],  rb[3]};
            row[1] = float4{rb[4],  rb[5],  rb[6],  rb[7]};
            row[2] = float4{rb[8],  rb[9],  rb[10], rb[11]};
            row[3] = float4{rb[12], rb[13], rb[14], rb[15]};
            row[4] = float4{rb[16], rb[17], rb[18], rb[19]};
            // angular pairs: (l0 m0),(l1 m01),(l1 m22),(l2 m45... ) — global ang idx = offm+m
            // pidx: 0:(an0,an0) 1:(an1,an2) 2:(an3,an3) 3:(an4,an5) 4:(an6,an7)
            //       5:(an8,an8) 6:(an9,an10) 7:(an11,an12) 8:(an13,an14) 9:(an15,an15)
            row[5] = float4{an[0],  an[0],  an[1],  an[2]};
            row[6] = float4{an[3],  an[3],  an[4],  an[5]};
            row[7] = float4{an[6],  an[7],  an[8],  an[8]};
            row[8] = float4{an[9],  an[10], an[11], an[12]};
            row[9] = float4{an[13], an[14], an[15], an[15]};
            row[10] = spv;
        }
        __builtin_amdgcn_wave_barrier();   // keep compiler from moving reads above writes
                                           // (DS ops within a wave complete in order)
        // ---- Phase B: 43 lanes accumulate ----
        if (active) {
            for (int s = 0; s < cnt; ++s) {
                const float* f = &F[s][0];
                const float4 rq = *(const float4*)(f + n0);
                const float2 ap = *(const float2*)(f + 20 + 2*pidx);
                const float4 sv = *(const float4*)(f + 40);
                const float rr[4] = {rq.x, rq.y, rq.z, rq.w};
                const float aa[2] = {ap.x, ap.y};
                #pragma unroll
                for (int mi = 0; mi < 2; ++mi) {
                    #pragma unroll
                    for (int ni = 0; ni < 4; ++ni) {
                        const float p = rr[ni] * aa[mi];
                        float4& A = acc[mi*4 + ni];
                        A.x += p * sv.x; A.y += p * sv.y; A.z += p * sv.z; A.w += p * sv.w;
                    }
                }
            }
        }
        __builtin_amdgcn_wave_barrier();   // order Phase B reads before next batch's writes
    }

    if (active) {
        float* ob = out + base + (size_t)atom * (size_t)stride;
        #pragma unroll
        for (int mi = 0; mi < 2; ++mi) {
            if (mi == 0 || m1 != m0) {
                const int m = mi ? m1 : m0;
                #pragma unroll
                for (int ni = 0; ni < 4; ++ni) {
                    const int n = n0 + ni;
                    if (n < nl) *(float4*)(ob + (size_t)(m*nl + n)*4) = acc[mi*4 + ni];
                }
            }
        }
    }
}

extern "C" void kernel_launch(void* const* d_in, const int* in_sizes, int n_in,
                              void* d_out, int out_size, void* d_ws, size_t ws_size,
                              hipStream_t stream) {
    const float* R    = (const float*)d_in[0];
    const int*   i_   = (const int*)  d_in[1];
    const int*   j_   = (const int*)  d_in[2];
    const int*   sp   = (const int*)  d_in[3];
    const float* emb  = (const float*)d_in[4];
    float* out = (float*)d_out;
    int*   starts = (int*)d_ws;   // 10001 ints

    seg_starts_kernel<<<(N_ATOMS + 256) / 256, 256, 0, stream>>>(i_, starts);
    sph_expand_kernel<<<N_ATOMS / 4, 256, 0, stream>>>(R, starts, j_, sp, emb, out);
}